// Round 1
// baseline (1719.406 us; speedup 1.0000x reference)
//
#include <hip/hip_runtime.h>
#include <cstdint>
#include <cstddef>

using u16 = unsigned short;
using f32x4 = __attribute__((ext_vector_type(4))) float;
using bf8   = __attribute__((ext_vector_type(8))) short;   // 8 bf16 in 4 VGPRs

#define DEVFN __device__ __forceinline__

constexpr int BB  = 2;
constexpr int LQ  = 2048;
constexpr int LKV = 4096;
constexpr int DD  = 2048;
constexpr int NH  = 16;
constexpr int HDm = 128;
constexpr float ATTN_SCALE = 0.08838834764831845f;  // 128^-0.5
constexpr float LN_EPS = 1e-6f;

DEVFN u16 f2bf(float f) {
  unsigned u = __builtin_bit_cast(unsigned, f);
  u += 0x7fffu + ((u >> 16) & 1u);          // RNE
  return (u16)(u >> 16);
}
DEVFN float bf2f(u16 h) { return __builtin_bit_cast(float, (unsigned)h << 16); }
DEVFN f32x4 mfma16(bf8 a, bf8 b, f32x4 c) {
  return __builtin_amdgcn_mfma_f32_16x16x32_bf16(a, b, c, 0, 0, 0);
}

// ---------------- f32 -> bf16 convert (4 el/thread) ----------------
__global__ __launch_bounds__(256) void k_cvt(const float4* __restrict__ in,
                                             ushort4* __restrict__ out, int n4) {
  int i = blockIdx.x * 256 + threadIdx.x;
  if (i >= n4) return;
  float4 v = in[i];
  ushort4 o;
  o.x = f2bf(v.x); o.y = f2bf(v.y); o.z = f2bf(v.z); o.w = f2bf(v.w);
  out[i] = o;
}

// ---------------- bf16 NT GEMM: Y[M,N] = X[M,K] * W[N,K]^T + bias[N] -------
// 128x128 tile, BK=64, 4 waves (each 64x64 quadrant of 4x4 16x16 frags)
template <int OUTF32>
__global__ __launch_bounds__(256) void k_gemm_nt(const u16* __restrict__ X,
                                                 const u16* __restrict__ Wt,
                                                 const float* __restrict__ bias,
                                                 void* __restrict__ Y,
                                                 int M, int N, int K) {
  __shared__ __align__(16) u16 As[128 * 64];
  __shared__ __align__(16) u16 Bs[128 * 64];
  const int tid = threadIdx.x;
  const int w = tid >> 6, l = tid & 63;
  const int m0 = blockIdx.x * 128, n0 = blockIdx.y * 128;
  const int wr = w >> 1, wc = w & 1;
  const int srow = l >> 3, scol = (l & 7) * 8;   // staging: 8 lanes/row, 8 el each
  const int lr = l & 15, lk = (l >> 4) * 8;
  f32x4 acc[4][4] = {};

  for (int k0 = 0; k0 < K; k0 += 64) {
#pragma unroll
    for (int i = 0; i < 4; ++i) {
      int r = w * 32 + i * 8 + srow;
      *(int4*)&As[r * 64 + scol] = *(const int4*)&X[(size_t)(m0 + r) * K + k0 + scol];
      *(int4*)&Bs[r * 64 + scol] = *(const int4*)&Wt[(size_t)(n0 + r) * K + k0 + scol];
    }
    __syncthreads();
    bf8 af[4][2], bfr[4][2];
#pragma unroll
    for (int mi = 0; mi < 4; ++mi)
#pragma unroll
      for (int kk = 0; kk < 2; ++kk)
        af[mi][kk] = *(const bf8*)&As[(wr * 64 + mi * 16 + lr) * 64 + kk * 32 + lk];
#pragma unroll
    for (int ni = 0; ni < 4; ++ni)
#pragma unroll
      for (int kk = 0; kk < 2; ++kk)
        bfr[ni][kk] = *(const bf8*)&Bs[(wc * 64 + ni * 16 + lr) * 64 + kk * 32 + lk];
#pragma unroll
    for (int kk = 0; kk < 2; ++kk)
#pragma unroll
      for (int mi = 0; mi < 4; ++mi)
#pragma unroll
        for (int ni = 0; ni < 4; ++ni)
          acc[mi][ni] = mfma16(af[mi][kk], bfr[ni][kk], acc[mi][ni]);
    __syncthreads();
  }
  const int lrg = (l >> 4) * 4;
#pragma unroll
  for (int ni = 0; ni < 4; ++ni) {
    int n = n0 + wc * 64 + ni * 16 + lr;
    float bv = bias[n];
#pragma unroll
    for (int mi = 0; mi < 4; ++mi) {
      int mb = m0 + wr * 64 + mi * 16 + lrg;
#pragma unroll
      for (int r = 0; r < 4; ++r) {
        float v = acc[mi][ni][r] + bv;
        if (OUTF32) ((float*)Y)[(size_t)(mb + r) * N + n] = v;
        else        ((u16*)Y)[(size_t)(mb + r) * N + n] = f2bf(v);
      }
    }
  }
}

// ---------------- per-head LayerNorm over contiguous 128-el segments -------
// buffer is [tokens, D]; since D = H*128, seg s = contiguous chunk s*128.
template <bool SCALEQ>
__global__ __launch_bounds__(256) void k_headln(u16* __restrict__ Y,
                                                const float* __restrict__ g,
                                                const float* __restrict__ b,
                                                int nseg) {
  int seg = blockIdx.x * 4 + (threadIdx.x >> 6);
  int l = threadIdx.x & 63;
  if (seg >= nseg) return;
  size_t base = (size_t)seg * 128 + l * 2;
  unsigned raw = *(const unsigned*)&Y[base];
  float x0 = bf2f((u16)(raw & 0xffff)), x1 = bf2f((u16)(raw >> 16));
  float s = x0 + x1, ss = x0 * x0 + x1 * x1;
#pragma unroll
  for (int m = 1; m < 64; m <<= 1) {
    s += __shfl_xor(s, m);
    ss += __shfl_xor(ss, m);
  }
  float mean = s * (1.f / 128.f);
  float var = ss * (1.f / 128.f) - mean * mean;
  float rs = rsqrtf(var + LN_EPS);
  float o0 = (x0 - mean) * rs * g[l * 2] + b[l * 2];
  float o1 = (x1 - mean) * rs * g[l * 2 + 1] + b[l * 2 + 1];
  if (SCALEQ) { o0 *= ATTN_SCALE; o1 *= ATTN_SCALE; }
  *(unsigned*)&Y[base] = (unsigned)f2bf(o0) | ((unsigned)f2bf(o1) << 16);
}

// ---------------- V transpose: [B,Lkv,D] -> [B*H, Hd, Lkv] -----------------
__global__ __launch_bounds__(256) void k_vtrans(const u16* __restrict__ V,
                                                u16* __restrict__ Vt) {
  int bh = blockIdx.y;             // 0..31
  int b = bh >> 4, h = bh & 15;
  int kv0 = blockIdx.x * 64;
  __shared__ __align__(16) u16 t[64][136];
  int tid = threadIdx.x;
  int r = tid >> 4, c = (tid & 15) * 8;
#pragma unroll
  for (int i = 0; i < 4; ++i) {
    int row = i * 16 + r;
    *(int4*)&t[row][c] = *(const int4*)&V[((size_t)b * LKV + kv0 + row) * DD + h * HDm + c];
  }
  __syncthreads();
  int hd_ = tid >> 3, kvc = (tid & 7) * 8;
#pragma unroll
  for (int i = 0; i < 4; ++i) {
    int hd = i * 32 + hd_;
    u16 tmp[8] __attribute__((aligned(16)));
#pragma unroll
    for (int j = 0; j < 8; ++j) tmp[j] = t[kvc + j][hd];
    *(int4*)&Vt[((size_t)bh * HDm + hd) * LKV + kv0 + kvc] = *(const int4*)tmp;
  }
}

// ---------------- fused attention ------------------------------------------
// grid: (Lq/64, B*H); 4 waves, each owns 16 q rows. Two passes over KV:
//  A: online max+sum stats.  B: recompute S, write normalized fp32 weights,
//  P->bf16 in LDS, PV accumulate. Q pre-scaled by ATTN_SCALE in LN.
__global__ __launch_bounds__(256) void k_attn(const u16* __restrict__ Qp,
                                              const u16* __restrict__ Kp,
                                              const u16* __restrict__ Vt,
                                              float* __restrict__ Wout,
                                              u16* __restrict__ AO) {
  const int bh = blockIdx.y;
  const int b = bh >> 4, h = bh & 15;
  const int q0 = blockIdx.x * 64;
  const int tid = threadIdx.x, w = tid >> 6, l = tid & 63;
  const int lr = l & 15, lk = (l >> 4) * 8, lrg = (l >> 4) * 4;
  __shared__ __align__(16) u16 Ks[64 * 128];
  __shared__ __align__(16) u16 Vs[128 * 64];
  __shared__ __align__(16) u16 Ps[4][16 * 72];   // per-wave, rows padded to 72

  // hoist Q fragments (A-frag: row = lr, k = lk + kc*32)
  bf8 qf[4];
  const int qrow_a = q0 + w * 16 + lr;
#pragma unroll
  for (int kc = 0; kc < 4; ++kc)
    qf[kc] = *(const bf8*)&Qp[((size_t)b * LQ + qrow_a) * DD + h * HDm + kc * 32 + lk];

  float mrow[4], lsum[4];
#pragma unroll
  for (int r = 0; r < 4; ++r) { mrow[r] = -1e30f; lsum[r] = 0.f; }

  // ---- pass A: stats
  for (int kv0 = 0; kv0 < LKV; kv0 += 64) {
#pragma unroll
    for (int i = 0; i < 4; ++i) {            // stage K tile [64][128]
      int row = w * 16 + i * 4 + (l >> 4);
      *(int4*)&Ks[row * 128 + lr * 8] =
          *(const int4*)&Kp[((size_t)b * LKV + kv0 + row) * DD + h * HDm + lr * 8];
    }
    __syncthreads();
    f32x4 s[4];
#pragma unroll
    for (int ni = 0; ni < 4; ++ni) {
      s[ni] = f32x4{0.f, 0.f, 0.f, 0.f};
#pragma unroll
      for (int kc = 0; kc < 4; ++kc) {
        bf8 kf = *(const bf8*)&Ks[(ni * 16 + lr) * 128 + kc * 32 + lk];
        s[ni] = mfma16(qf[kc], kf, s[ni]);
      }
    }
#pragma unroll
    for (int r = 0; r < 4; ++r) {
      float tm = fmaxf(fmaxf(s[0][r], s[1][r]), fmaxf(s[2][r], s[3][r]));
#pragma unroll
      for (int m = 1; m < 16; m <<= 1) tm = fmaxf(tm, __shfl_xor(tm, m));
      float mn = fmaxf(mrow[r], tm);
      float sum = 0.f;
#pragma unroll
      for (int ni = 0; ni < 4; ++ni) sum += __expf(s[ni][r] - mn);
#pragma unroll
      for (int m = 1; m < 16; m <<= 1) sum += __shfl_xor(sum, m);
      lsum[r] = lsum[r] * __expf(mrow[r] - mn) + sum;
      mrow[r] = mn;
    }
    __syncthreads();
  }
  float inv[4];
#pragma unroll
  for (int r = 0; r < 4; ++r) inv[r] = 1.f / lsum[r];

  // ---- pass B: weights + PV
  f32x4 oacc[8] = {};
  for (int kv0 = 0; kv0 < LKV; kv0 += 64) {
#pragma unroll
    for (int i = 0; i < 4; ++i) {            // stage K tile
      int row = w * 16 + i * 4 + (l >> 4);
      *(int4*)&Ks[row * 128 + lr * 8] =
          *(const int4*)&Kp[((size_t)b * LKV + kv0 + row) * DD + h * HDm + lr * 8];
    }
#pragma unroll
    for (int i = 0; i < 4; ++i) {            // stage Vt tile [128][64]
      int hd = w * 32 + i * 8 + (l >> 3);
      *(int4*)&Vs[hd * 64 + (l & 7) * 8] =
          *(const int4*)&Vt[((size_t)bh * HDm + hd) * LKV + kv0 + (l & 7) * 8];
    }
    __syncthreads();
    f32x4 s[4];
#pragma unroll
    for (int ni = 0; ni < 4; ++ni) {
      s[ni] = f32x4{0.f, 0.f, 0.f, 0.f};
#pragma unroll
      for (int kc = 0; kc < 4; ++kc) {
        bf8 kf = *(const bf8*)&Ks[(ni * 16 + lr) * 128 + kc * 32 + lk];
        s[ni] = mfma16(qf[kc], kf, s[ni]);
      }
    }
#pragma unroll
    for (int ni = 0; ni < 4; ++ni) {
#pragma unroll
      for (int r = 0; r < 4; ++r) {
        float p = __expf(s[ni][r] - mrow[r]) * inv[r];
        Wout[((size_t)bh * LQ + q0 + w * 16 + lrg + r) * LKV + kv0 + ni * 16 + lr] = p;
        Ps[w][(lrg + r) * 72 + ni * 16 + lr] = f2bf(p);
      }
    }
    __syncthreads();                          // Ps cross-lane visibility
#pragma unroll
    for (int kk = 0; kk < 2; ++kk) {
      bf8 pf = *(const bf8*)&Ps[w][lr * 72 + kk * 32 + lk];
#pragma unroll
      for (int c = 0; c < 8; ++c) {
        bf8 vf = *(const bf8*)&Vs[(c * 16 + lr) * 64 + kk * 32 + lk];
        oacc[c] = mfma16(pf, vf, oacc[c]);
      }
    }
    __syncthreads();
  }
  // epilogue: AO [B, Lq, D] bf16
#pragma unroll
  for (int c = 0; c < 8; ++c)
#pragma unroll
    for (int r = 0; r < 4; ++r)
      AO[((size_t)b * LQ + q0 + w * 16 + lrg + r) * DD + h * HDm + c * 16 + lr] =
          f2bf(oacc[c][r]);
}

// ---------------------------------------------------------------------------
extern "C" void kernel_launch(void* const* d_in, const int* in_sizes, int n_in,
                              void* d_out, int out_size, void* d_ws, size_t ws_size,
                              hipStream_t stream) {
  const float* hs   = (const float*)d_in[0];
  const float* cas  = (const float*)d_in[1];
  const float* q_w  = (const float*)d_in[2];
  const float* q_b  = (const float*)d_in[3];
  const float* k_w  = (const float*)d_in[4];
  const float* k_b  = (const float*)d_in[5];
  const float* v_w  = (const float*)d_in[6];
  const float* v_b  = (const float*)d_in[7];
  const float* o_w  = (const float*)d_in[8];
  const float* o_b  = (const float*)d_in[9];
  const float* qn_g = (const float*)d_in[10];
  const float* qn_b = (const float*)d_in[11];
  const float* kn_g = (const float*)d_in[12];
  const float* kn_b = (const float*)d_in[13];

  float* out_attn = (float*)d_out;
  float* out_w    = out_attn + (size_t)BB * LQ * DD;

  // workspace carve-up (bytes)
  constexpr size_t SZ_Q  = (size_t)BB * LQ * DD * 2;    // 16.8 MB (hs / Qp / AO)
  constexpr size_t SZ_KV = (size_t)BB * LKV * DD * 2;   // 33.6 MB
  constexpr size_t SZ_W  = (size_t)DD * DD * 2;         // 8.4 MB
  char* p = (char*)d_ws;
  u16* hsb  = (u16*)p;              p += SZ_Q;
  u16* casb = (u16*)p;              p += SZ_KV;
  u16* qwb  = (u16*)p;              p += SZ_W;
  u16* kwb  = (u16*)p;              p += SZ_W;
  u16* vwb  = (u16*)p;              p += SZ_W;
  u16* owb  = (u16*)p;              p += SZ_W;
  u16* Qp   = (u16*)p;              p += SZ_Q;
  u16* Kp   = (u16*)p;              p += SZ_KV;
  u16* Vp   = (u16*)p;              p += SZ_KV;
  u16* Vtp  = (u16*)p;              p += SZ_KV;
  u16* AO   = (u16*)p;              p += SZ_Q;

  // 1) convert to bf16
  auto cvt = [&](const float* src, u16* dst, size_t n) {
    int n4 = (int)(n / 4);
    k_cvt<<<dim3((n4 + 255) / 256), dim3(256), 0, stream>>>(
        (const float4*)src, (ushort4*)dst, n4);
  };
  cvt(hs,  hsb,  (size_t)BB * LQ * DD);
  cvt(cas, casb, (size_t)BB * LKV * DD);
  cvt(q_w, qwb, (size_t)DD * DD);
  cvt(k_w, kwb, (size_t)DD * DD);
  cvt(v_w, vwb, (size_t)DD * DD);
  cvt(o_w, owb, (size_t)DD * DD);

  // 2) projections
  k_gemm_nt<0><<<dim3(BB * LQ / 128, DD / 128), dim3(256), 0, stream>>>(
      hsb, qwb, q_b, Qp, BB * LQ, DD, DD);
  k_gemm_nt<0><<<dim3(BB * LKV / 128, DD / 128), dim3(256), 0, stream>>>(
      casb, kwb, k_b, Kp, BB * LKV, DD, DD);
  k_gemm_nt<0><<<dim3(BB * LKV / 128, DD / 128), dim3(256), 0, stream>>>(
      casb, vwb, v_b, Vp, BB * LKV, DD, DD);

  // 3) per-head LayerNorm (Q also pre-scaled by Hd^-0.5)
  k_headln<true><<<dim3(BB * LQ * NH / 4), dim3(256), 0, stream>>>(
      Qp, qn_g, qn_b, BB * LQ * NH);
  k_headln<false><<<dim3(BB * LKV * NH / 4), dim3(256), 0, stream>>>(
      Kp, kn_g, kn_b, BB * LKV * NH);

  // 4) V transpose to [B*H, Hd, Lkv]
  k_vtrans<<<dim3(LKV / 64, BB * NH), dim3(256), 0, stream>>>(Vp, Vtp);

  // 5) fused attention (weights out fp32 + AO bf16)
  k_attn<<<dim3(LQ / 64, BB * NH), dim3(256), 0, stream>>>(Qp, Kp, Vtp, out_w, AO);

  // 6) O projection -> fp32 into d_out
  k_gemm_nt<1><<<dim3(BB * LQ / 128, DD / 128), dim3(256), 0, stream>>>(
      AO, owb, o_b, out_attn, BB * LQ, DD, DD);
}

// Round 2
// 1065.710 us; speedup vs baseline: 1.6134x; 1.6134x over previous
//
#include <hip/hip_runtime.h>
#include <cstdint>
#include <cstddef>

using u16 = unsigned short;
using f32x4 = __attribute__((ext_vector_type(4))) float;
using bf8   = __attribute__((ext_vector_type(8))) short;   // 8 bf16 in 4 VGPRs

#define DEVFN __device__ __forceinline__

constexpr int BB  = 2;
constexpr int LQ  = 2048;
constexpr int LKV = 4096;
constexpr int DD  = 2048;
constexpr int NH  = 16;
constexpr int HDm = 128;
constexpr float ATTN_SCALE = 0.08838834764831845f;  // 128^-0.5
constexpr float LN_EPS = 1e-6f;

DEVFN u16 f2bf(float f) {
  unsigned u = __builtin_bit_cast(unsigned, f);
  u += 0x7fffu + ((u >> 16) & 1u);          // RNE
  return (u16)(u >> 16);
}
DEVFN float bf2f(u16 h) { return __builtin_bit_cast(float, (unsigned)h << 16); }
DEVFN f32x4 mfma16(bf8 a, bf8 b, f32x4 c) {
  return __builtin_amdgcn_mfma_f32_16x16x32_bf16(a, b, c, 0, 0, 0);
}
// async global->LDS, 16B/lane, lane i lands at lds + i*16 (wave-uniform lds base)
DEVFN void gl16(const void* g, void* l) {
  __builtin_amdgcn_global_load_lds(
      (const __attribute__((address_space(1))) void*)g,
      (__attribute__((address_space(3))) void*)l, 16, 0, 0);
}

// ---------------- f32 -> bf16 convert (4 el/thread) ----------------
__global__ __launch_bounds__(256) void k_cvt(const float4* __restrict__ in,
                                             ushort4* __restrict__ out, int n4) {
  int i = blockIdx.x * 256 + threadIdx.x;
  if (i >= n4) return;
  float4 v = in[i];
  ushort4 o;
  o.x = f2bf(v.x); o.y = f2bf(v.y); o.z = f2bf(v.z); o.w = f2bf(v.w);
  out[i] = o;
}

// ---------------- bf16 NT GEMM: Y[M,N] = X[M,K] * W[N,K]^T + bias[N] -------
// 128x128 tile, BK=64, 4 waves. global_load_lds staging with pre-swizzled
// source (rule #21: linear LDS dest + inv-swz source + swz read).
// LDS tile rows are 128 B; swizzle byte ^= ((row&7)<<4) kills the 16-way
// read conflict (16 lanes, same col, stride-128B rows).
template <int OUTF32>
__global__ __launch_bounds__(256) void k_gemm_nt(const u16* __restrict__ X,
                                                 const u16* __restrict__ Wt,
                                                 const float* __restrict__ bias,
                                                 void* __restrict__ Y,
                                                 int M, int N, int K) {
  __shared__ __align__(16) u16 As[128 * 64];
  __shared__ __align__(16) u16 Bs[128 * 64];
  const int tid = threadIdx.x;
  const int w = tid >> 6, l = tid & 63;
  const int m0 = blockIdx.x * 128, n0 = blockIdx.y * 128;
  const int wr = w >> 1, wc = w & 1;
  const int lr = l & 15, lk = (l >> 4) * 8;
  const int rsw = (l & 7) << 3;               // read-side swizzle (u16 units)
  // staging geometry: 8 rows/call, lane covers row rbase+(l>>3), colbyte (l&7)*16
  const int srow = l >> 3;
  const int scb = (l & 7) * 16;
  f32x4 acc[4][4] = {};

  for (int k0 = 0; k0 < K; k0 += 64) {
#pragma unroll
    for (int i = 0; i < 4; ++i) {
      int rbase = w * 32 + i * 8;
      int row = rbase + srow;
      int cb = scb ^ ((row & 7) << 4);        // inverse-swizzled source col (bytes)
      gl16((const char*)&X[(size_t)(m0 + row) * K + k0] + cb, &As[rbase * 64]);
      gl16((const char*)&Wt[(size_t)(n0 + row) * K + k0] + cb, &Bs[rbase * 64]);
    }
    __syncthreads();
    bf8 af[4][2], bfr[4][2];
#pragma unroll
    for (int mi = 0; mi < 4; ++mi)
#pragma unroll
      for (int kk = 0; kk < 2; ++kk)
        af[mi][kk] = *(const bf8*)&As[(wr * 64 + mi * 16 + lr) * 64 + ((kk * 32 + lk) ^ rsw)];
#pragma unroll
    for (int ni = 0; ni < 4; ++ni)
#pragma unroll
      for (int kk = 0; kk < 2; ++kk)
        bfr[ni][kk] = *(const bf8*)&Bs[(wc * 64 + ni * 16 + lr) * 64 + ((kk * 32 + lk) ^ rsw)];
#pragma unroll
    for (int kk = 0; kk < 2; ++kk)
#pragma unroll
      for (int mi = 0; mi < 4; ++mi)
#pragma unroll
        for (int ni = 0; ni < 4; ++ni)
          acc[mi][ni] = mfma16(af[mi][kk], bfr[ni][kk], acc[mi][ni]);
    __syncthreads();
  }
  const int lrg = (l >> 4) * 4;
#pragma unroll
  for (int ni = 0; ni < 4; ++ni) {
    int n = n0 + wc * 64 + ni * 16 + lr;
    float bv = bias[n];
#pragma unroll
    for (int mi = 0; mi < 4; ++mi) {
      int mb = m0 + wr * 64 + mi * 16 + lrg;
#pragma unroll
      for (int r = 0; r < 4; ++r) {
        float v = acc[mi][ni][r] + bv;
        if (OUTF32) ((float*)Y)[(size_t)(mb + r) * N + n] = v;
        else        ((u16*)Y)[(size_t)(mb + r) * N + n] = f2bf(v);
      }
    }
  }
}

// ---------------- per-head LayerNorm over contiguous 128-el segments -------
template <bool SCALEQ>
__global__ __launch_bounds__(256) void k_headln(u16* __restrict__ Y,
                                                const float* __restrict__ g,
                                                const float* __restrict__ b,
                                                int nseg) {
  int seg = blockIdx.x * 4 + (threadIdx.x >> 6);
  int l = threadIdx.x & 63;
  if (seg >= nseg) return;
  size_t base = (size_t)seg * 128 + l * 2;
  unsigned raw = *(const unsigned*)&Y[base];
  float x0 = bf2f((u16)(raw & 0xffff)), x1 = bf2f((u16)(raw >> 16));
  float s = x0 + x1, ss = x0 * x0 + x1 * x1;
#pragma unroll
  for (int m = 1; m < 64; m <<= 1) {
    s += __shfl_xor(s, m);
    ss += __shfl_xor(ss, m);
  }
  float mean = s * (1.f / 128.f);
  float var = ss * (1.f / 128.f) - mean * mean;
  float rs = rsqrtf(var + LN_EPS);
  float o0 = (x0 - mean) * rs * g[l * 2] + b[l * 2];
  float o1 = (x1 - mean) * rs * g[l * 2 + 1] + b[l * 2 + 1];
  if (SCALEQ) { o0 *= ATTN_SCALE; o1 *= ATTN_SCALE; }
  *(unsigned*)&Y[base] = (unsigned)f2bf(o0) | ((unsigned)f2bf(o1) << 16);
}

// ---------------- V transpose: [B,Lkv,D] -> [B*H, Hd, Lkv] -----------------
__global__ __launch_bounds__(256) void k_vtrans(const u16* __restrict__ V,
                                                u16* __restrict__ Vt) {
  int bh = blockIdx.y;
  int b = bh >> 4, h = bh & 15;
  int kv0 = blockIdx.x * 64;
  __shared__ __align__(16) u16 t[64][136];
  int tid = threadIdx.x;
  int r = tid >> 4, c = (tid & 15) * 8;
#pragma unroll
  for (int i = 0; i < 4; ++i) {
    int row = i * 16 + r;
    *(int4*)&t[row][c] = *(const int4*)&V[((size_t)b * LKV + kv0 + row) * DD + h * HDm + c];
  }
  __syncthreads();
  int hd_ = tid >> 3, kvc = (tid & 7) * 8;
#pragma unroll
  for (int i = 0; i < 4; ++i) {
    int hd = i * 32 + hd_;
    u16 tmp[8] __attribute__((aligned(16)));
#pragma unroll
    for (int j = 0; j < 8; ++j) tmp[j] = t[kvc + j][hd];
    *(int4*)&Vt[((size_t)bh * HDm + hd) * LKV + kv0 + kvc] = *(const int4*)tmp;
  }
}

// ---------------- fused attention ------------------------------------------
// grid: 1024 1D (XCD-swizzled); 4 waves, each owns 16 q rows. Two passes:
//  A: online max+sum stats.  B: recompute S, write normalized fp32 weights,
//  P->bf16 in LDS, PV accumulate. Q pre-scaled by ATTN_SCALE in LN.
// All LDS tiles XOR-swizzled (T2) and staged via global_load_lds (rule #21).
// LDS = 16K(Ks)+16K(Vs)+8K(Ps) = 40960 B -> 4 blocks/CU.
__global__ __launch_bounds__(256) void k_attn(const u16* __restrict__ Qp,
                                              const u16* __restrict__ Kp,
                                              const u16* __restrict__ Vt,
                                              float* __restrict__ Wout,
                                              u16* __restrict__ AO) {
  // XCD-aware swizzle: 1024 blocks, 8 XCDs -> each XCD gets 4 consecutive bh
  const int g = blockIdx.x;
  const int work = (g & 7) * 128 + (g >> 3);
  const int bh = work >> 5;
  const int b = bh >> 4, h = bh & 15;
  const int q0 = (work & 31) * 64;
  const int tid = threadIdx.x, w = tid >> 6, l = tid & 63;
  const int lr = l & 15, lk = (l >> 4) * 8, lrg = (l >> 4) * 4;
  const int rsw = (l & 7) << 3;               // read swizzle, u16 units
  __shared__ __align__(16) u16 Ks[64 * 128];
  __shared__ __align__(16) u16 Vs[128 * 64];
  __shared__ __align__(16) u16 Ps[4][16 * 64];

  // hoist Q fragments (A-frag: row = lr, k = lk + kc*32)
  bf8 qf[4];
  {
    const u16* qb = &Qp[((size_t)b * LQ + q0 + w * 16 + lr) * DD + h * HDm];
#pragma unroll
    for (int kc = 0; kc < 4; ++kc) qf[kc] = *(const bf8*)(qb + kc * 32 + lk);
  }

  // staging: Ks 64 rows x 256 B (4 rows/call), Vs 128 rows x 128 B (8 rows/call)
  auto stageK = [&](int kv0) {
#pragma unroll
    for (int i = 0; i < 4; ++i) {
      int rbase = w * 16 + i * 4;
      int row = rbase + (l >> 4);
      int cb = ((l & 15) * 16) ^ ((row & 7) << 4);
      gl16((const char*)&Kp[((size_t)b * LKV + kv0 + row) * DD + h * HDm] + cb,
           &Ks[rbase * 128]);
    }
  };
  auto stageV = [&](int kv0) {
#pragma unroll
    for (int i = 0; i < 4; ++i) {
      int rbase = w * 32 + i * 8;
      int row = rbase + (l >> 3);
      int cb = ((l & 7) * 16) ^ ((row & 7) << 4);
      gl16((const char*)&Vt[((size_t)bh * HDm + row) * LKV + kv0] + cb,
           &Vs[rbase * 64]);
    }
  };

  float mrow[4], lsum[4];
#pragma unroll
  for (int r = 0; r < 4; ++r) { mrow[r] = -1e30f; lsum[r] = 0.f; }

  // ---- pass A: stats
  for (int kv0 = 0; kv0 < LKV; kv0 += 64) {
    stageK(kv0);
    __syncthreads();
    f32x4 s[4];
#pragma unroll
    for (int ni = 0; ni < 4; ++ni) {
      s[ni] = f32x4{0.f, 0.f, 0.f, 0.f};
#pragma unroll
      for (int kc = 0; kc < 4; ++kc) {
        bf8 kf = *(const bf8*)&Ks[(ni * 16 + lr) * 128 + ((kc * 32 + lk) ^ rsw)];
        s[ni] = mfma16(qf[kc], kf, s[ni]);
      }
    }
#pragma unroll
    for (int r = 0; r < 4; ++r) {
      float tm = fmaxf(fmaxf(s[0][r], s[1][r]), fmaxf(s[2][r], s[3][r]));
#pragma unroll
      for (int m = 1; m < 16; m <<= 1) tm = fmaxf(tm, __shfl_xor(tm, m));
      float mn = fmaxf(mrow[r], tm);
      float sum = 0.f;
#pragma unroll
      for (int ni = 0; ni < 4; ++ni) sum += __expf(s[ni][r] - mn);
#pragma unroll
      for (int m = 1; m < 16; m <<= 1) sum += __shfl_xor(sum, m);
      lsum[r] = lsum[r] * __expf(mrow[r] - mn) + sum;
      mrow[r] = mn;
    }
    __syncthreads();            // protect Ks from next stage
  }
  float inv[4];
#pragma unroll
  for (int r = 0; r < 4; ++r) inv[r] = 1.f / lsum[r];

  // ---- pass B: weights + PV (3 barriers/iter: staged|Ps-visible|read-done)
  f32x4 oacc[8] = {};
  for (int kv0 = 0; kv0 < LKV; kv0 += 64) {
    stageK(kv0);
    stageV(kv0);
    __syncthreads();
    f32x4 s[4];
#pragma unroll
    for (int ni = 0; ni < 4; ++ni) {
      s[ni] = f32x4{0.f, 0.f, 0.f, 0.f};
#pragma unroll
      for (int kc = 0; kc < 4; ++kc) {
        bf8 kf = *(const bf8*)&Ks[(ni * 16 + lr) * 128 + ((kc * 32 + lk) ^ rsw)];
        s[ni] = mfma16(qf[kc], kf, s[ni]);
      }
    }
#pragma unroll
    for (int ni = 0; ni < 4; ++ni) {
#pragma unroll
      for (int r = 0; r < 4; ++r) {
        float p = __expf(s[ni][r] - mrow[r]) * inv[r];
        Wout[((size_t)bh * LQ + q0 + w * 16 + lrg + r) * LKV + kv0 + ni * 16 + lr] = p;
        int row = lrg + r;
        Ps[w][row * 64 + ((ni * 16 + lr) ^ ((row & 7) << 3))] = f2bf(p);
      }
    }
    __syncthreads();                          // Ps cross-lane visibility
#pragma unroll
    for (int kk = 0; kk < 2; ++kk) {
      bf8 pf = *(const bf8*)&Ps[w][lr * 64 + ((kk * 32 + lk) ^ rsw)];
#pragma unroll
      for (int c = 0; c < 8; ++c) {
        bf8 vf = *(const bf8*)&Vs[(c * 16 + lr) * 64 + ((kk * 32 + lk) ^ rsw)];
        oacc[c] = mfma16(pf, vf, oacc[c]);
      }
    }
    __syncthreads();                          // protect Ks/Vs/Ps from next stage
  }
  // epilogue: AO [B, Lq, D] bf16
#pragma unroll
  for (int c = 0; c < 8; ++c)
#pragma unroll
    for (int r = 0; r < 4; ++r)
      AO[((size_t)b * LQ + q0 + w * 16 + lrg + r) * DD + h * HDm + c * 16 + lr] =
          f2bf(oacc[c][r]);
}

// ---------------------------------------------------------------------------
extern "C" void kernel_launch(void* const* d_in, const int* in_sizes, int n_in,
                              void* d_out, int out_size, void* d_ws, size_t ws_size,
                              hipStream_t stream) {
  const float* hs   = (const float*)d_in[0];
  const float* cas  = (const float*)d_in[1];
  const float* q_w  = (const float*)d_in[2];
  const float* q_b  = (const float*)d_in[3];
  const float* k_w  = (const float*)d_in[4];
  const float* k_b  = (const float*)d_in[5];
  const float* v_w  = (const float*)d_in[6];
  const float* v_b  = (const float*)d_in[7];
  const float* o_w  = (const float*)d_in[8];
  const float* o_b  = (const float*)d_in[9];
  const float* qn_g = (const float*)d_in[10];
  const float* qn_b = (const float*)d_in[11];
  const float* kn_g = (const float*)d_in[12];
  const float* kn_b = (const float*)d_in[13];

  float* out_attn = (float*)d_out;
  float* out_w    = out_attn + (size_t)BB * LQ * DD;

  constexpr size_t SZ_Q  = (size_t)BB * LQ * DD * 2;
  constexpr size_t SZ_KV = (size_t)BB * LKV * DD * 2;
  constexpr size_t SZ_W  = (size_t)DD * DD * 2;
  char* p = (char*)d_ws;
  u16* hsb  = (u16*)p;              p += SZ_Q;
  u16* casb = (u16*)p;              p += SZ_KV;
  u16* qwb  = (u16*)p;              p += SZ_W;
  u16* kwb  = (u16*)p;              p += SZ_W;
  u16* vwb  = (u16*)p;              p += SZ_W;
  u16* owb  = (u16*)p;              p += SZ_W;
  u16* Qp   = (u16*)p;              p += SZ_Q;
  u16* Kp   = (u16*)p;              p += SZ_KV;
  u16* Vp   = (u16*)p;              p += SZ_KV;
  u16* Vtp  = (u16*)p;              p += SZ_KV;
  u16* AO   = (u16*)p;              p += SZ_Q;

  auto cvt = [&](const float* src, u16* dst, size_t n) {
    int n4 = (int)(n / 4);
    k_cvt<<<dim3((n4 + 255) / 256), dim3(256), 0, stream>>>(
        (const float4*)src, (ushort4*)dst, n4);
  };
  cvt(hs,  hsb,  (size_t)BB * LQ * DD);
  cvt(cas, casb, (size_t)BB * LKV * DD);
  cvt(q_w, qwb, (size_t)DD * DD);
  cvt(k_w, kwb, (size_t)DD * DD);
  cvt(v_w, vwb, (size_t)DD * DD);
  cvt(o_w, owb, (size_t)DD * DD);

  k_gemm_nt<0><<<dim3(BB * LQ / 128, DD / 128), dim3(256), 0, stream>>>(
      hsb, qwb, q_b, Qp, BB * LQ, DD, DD);
  k_gemm_nt<0><<<dim3(BB * LKV / 128, DD / 128), dim3(256), 0, stream>>>(
      casb, kwb, k_b, Kp, BB * LKV, DD, DD);
  k_gemm_nt<0><<<dim3(BB * LKV / 128, DD / 128), dim3(256), 0, stream>>>(
      casb, vwb, v_b, Vp, BB * LKV, DD, DD);

  k_headln<true><<<dim3(BB * LQ * NH / 4), dim3(256), 0, stream>>>(
      Qp, qn_g, qn_b, BB * LQ * NH);
  k_headln<false><<<dim3(BB * LKV * NH / 4), dim3(256), 0, stream>>>(
      Kp, kn_g, kn_b, BB * LKV * NH);

  k_vtrans<<<dim3(LKV / 64, BB * NH), dim3(256), 0, stream>>>(Vp, Vtp);

  k_attn<<<dim3(LQ / 64 * BB * NH), dim3(256), 0, stream>>>(Qp, Kp, Vtp, out_w, AO);

  k_gemm_nt<1><<<dim3(BB * LQ / 128, DD / 128), dim3(256), 0, stream>>>(
      AO, owb, o_b, out_attn, BB * LQ, DD, DD);
}

// Round 3
// 777.790 us; speedup vs baseline: 2.2106x; 1.3702x over previous
//
#include <hip/hip_runtime.h>
#include <cstdint>
#include <cstddef>

using u16 = unsigned short;
using f32x4 = __attribute__((ext_vector_type(4))) float;
using bf8   = __attribute__((ext_vector_type(8))) short;   // 8 bf16 in 4 VGPRs

#define DEVFN __device__ __forceinline__

constexpr int BB  = 2;
constexpr int LQ  = 2048;
constexpr int LKV = 4096;
constexpr int DD  = 2048;
constexpr int NH  = 16;
constexpr int HDm = 128;
constexpr float ATTN_SCALE = 0.08838834764831845f;  // 128^-0.5
constexpr float LN_EPS = 1e-6f;
// softmax fixed shift: LN guarantees |s| <= ||q*scale||*||k|| = 1*sqrt(128) ~ 11.4
constexpr float LOG2E  = 1.4426950408889634f;
constexpr float SHIFT2 = 17.312340490667562f;       // 12.0 * log2(e)

DEVFN u16 f2bf(float f) {
  unsigned u = __builtin_bit_cast(unsigned, f);
  u += 0x7fffu + ((u >> 16) & 1u);          // RNE
  return (u16)(u >> 16);
}
DEVFN float bf2f(u16 h) { return __builtin_bit_cast(float, (unsigned)h << 16); }
DEVFN f32x4 mfma16(bf8 a, bf8 b, f32x4 c) {
  return __builtin_amdgcn_mfma_f32_16x16x32_bf16(a, b, c, 0, 0, 0);
}
// async global->LDS, 16B/lane, lane i lands at lds + i*16 (wave-uniform lds base)
DEVFN void gl16(const void* g, void* l) {
  __builtin_amdgcn_global_load_lds(
      (const __attribute__((address_space(1))) void*)g,
      (__attribute__((address_space(3))) void*)l, 16, 0, 0);
}
DEVFN void barrier_hard() {                 // raw barrier + scheduler fence
  __builtin_amdgcn_s_barrier();
  __builtin_amdgcn_sched_barrier(0);
}

// ---------------- f32 -> bf16 convert (4 el/thread) ----------------
__global__ __launch_bounds__(256) void k_cvt(const float4* __restrict__ in,
                                             ushort4* __restrict__ out, int n4) {
  int i = blockIdx.x * 256 + threadIdx.x;
  if (i >= n4) return;
  float4 v = in[i];
  ushort4 o;
  o.x = f2bf(v.x); o.y = f2bf(v.y); o.z = f2bf(v.z); o.w = f2bf(v.w);
  out[i] = o;
}

// ---------------- bf16 NT GEMM: Y[M,N] = X[M,K] * W[N,K]^T + bias[N] -------
// 128x128 tile, BK=64, 4 waves, gl16 staging + XOR swizzle (round-2 verified).
// MODE: 0 = bf16 out; 1 = f32 out (nontemporal); 2 = bf16 + per-head LN;
//       3 = bf16 + per-head LN + ATTN_SCALE.  Head == the 128-col n-tile.
template <int MODE>
__global__ __launch_bounds__(256) void k_gemm_nt(const u16* __restrict__ X,
                                                 const u16* __restrict__ Wt,
                                                 const float* __restrict__ bias,
                                                 const float* __restrict__ lng,
                                                 const float* __restrict__ lnb,
                                                 void* __restrict__ Y,
                                                 int M, int N, int K) {
  __shared__ __align__(16) u16 As[128 * 64];
  __shared__ __align__(16) u16 Bs[128 * 64];
  __shared__ float Sm[2][128], Sq[2][128];
  const int tid = threadIdx.x;
  const int w = tid >> 6, l = tid & 63;
  const int m0 = blockIdx.x * 128, n0 = blockIdx.y * 128;
  const int wr = w >> 1, wc = w & 1;
  const int lr = l & 15, lk = (l >> 4) * 8;
  const int rsw = (l & 7) << 3;               // read-side swizzle (u16 units)
  const int srow = l >> 3;
  const int scb = (l & 7) * 16;
  f32x4 acc[4][4] = {};

  for (int k0 = 0; k0 < K; k0 += 64) {
#pragma unroll
    for (int i = 0; i < 4; ++i) {
      int rbase = w * 32 + i * 8;
      int row = rbase + srow;
      int cb = scb ^ ((row & 7) << 4);        // inverse-swizzled source col (bytes)
      gl16((const char*)&X[(size_t)(m0 + row) * K + k0] + cb, &As[rbase * 64]);
      gl16((const char*)&Wt[(size_t)(n0 + row) * K + k0] + cb, &Bs[rbase * 64]);
    }
    __syncthreads();
    bf8 af[4][2], bfr[4][2];
#pragma unroll
    for (int mi = 0; mi < 4; ++mi)
#pragma unroll
      for (int kk = 0; kk < 2; ++kk)
        af[mi][kk] = *(const bf8*)&As[(wr * 64 + mi * 16 + lr) * 64 + ((kk * 32 + lk) ^ rsw)];
#pragma unroll
    for (int ni = 0; ni < 4; ++ni)
#pragma unroll
      for (int kk = 0; kk < 2; ++kk)
        bfr[ni][kk] = *(const bf8*)&Bs[(wc * 64 + ni * 16 + lr) * 64 + ((kk * 32 + lk) ^ rsw)];
#pragma unroll
    for (int kk = 0; kk < 2; ++kk)
#pragma unroll
      for (int mi = 0; mi < 4; ++mi)
#pragma unroll
        for (int ni = 0; ni < 4; ++ni)
          acc[mi][ni] = mfma16(af[mi][kk], bfr[ni][kk], acc[mi][ni]);
    __syncthreads();
  }
  const int lrg = (l >> 4) * 4;

  // bias (pre-LN, matching reference: LN(x@W^T + b))
  float bv[4];
#pragma unroll
  for (int ni = 0; ni < 4; ++ni) bv[ni] = bias[n0 + wc * 64 + ni * 16 + lr];
#pragma unroll
  for (int mi = 0; mi < 4; ++mi)
#pragma unroll
    for (int ni = 0; ni < 4; ++ni)
#pragma unroll
      for (int r = 0; r < 4; ++r) acc[mi][ni][r] += bv[ni];

  if constexpr (MODE >= 2) {
    // per-row partial sums over this wave's 64 cols -> LDS -> combine
#pragma unroll
    for (int mi = 0; mi < 4; ++mi) {
#pragma unroll
      for (int r = 0; r < 4; ++r) {
        float ps = 0.f, pq = 0.f;
#pragma unroll
        for (int ni = 0; ni < 4; ++ni) {
          float v = acc[mi][ni][r];
          ps += v; pq += v * v;
        }
#pragma unroll
        for (int m = 1; m < 16; m <<= 1) {
          ps += __shfl_xor(ps, m);
          pq += __shfl_xor(pq, m);
        }
        if (lr == 0) {
          int rl = wr * 64 + mi * 16 + lrg + r;
          Sm[wc][rl] = ps; Sq[wc][rl] = pq;
        }
      }
    }
    __syncthreads();
    float gv[4], bbv[4];
#pragma unroll
    for (int ni = 0; ni < 4; ++ni) {
      int c = wc * 64 + ni * 16 + lr;          // col within head (n-tile aligned)
      gv[ni] = lng[c]; bbv[ni] = lnb[c];
    }
#pragma unroll
    for (int mi = 0; mi < 4; ++mi)
#pragma unroll
      for (int r = 0; r < 4; ++r) {
        int rl = wr * 64 + mi * 16 + lrg + r;
        float mean = (Sm[0][rl] + Sm[1][rl]) * (1.f / 128.f);
        float var  = (Sq[0][rl] + Sq[1][rl]) * (1.f / 128.f) - mean * mean;
        float rs = rsqrtf(var + LN_EPS);
#pragma unroll
        for (int ni = 0; ni < 4; ++ni) {
          float o = (acc[mi][ni][r] - mean) * rs * gv[ni] + bbv[ni];
          if (MODE == 3) o *= ATTN_SCALE;
          acc[mi][ni][r] = o;
        }
      }
  }

#pragma unroll
  for (int ni = 0; ni < 4; ++ni) {
    int n = n0 + wc * 64 + ni * 16 + lr;
#pragma unroll
    for (int mi = 0; mi < 4; ++mi) {
      int mb = m0 + wr * 64 + mi * 16 + lrg;
#pragma unroll
      for (int r = 0; r < 4; ++r) {
        float v = acc[mi][ni][r];
        if constexpr (MODE == 1)
          __builtin_nontemporal_store(v, &((float*)Y)[(size_t)(mb + r) * N + n]);
        else
          ((u16*)Y)[(size_t)(mb + r) * N + n] = f2bf(v);
      }
    }
  }
}

// ---------------- V transpose: [B,Lkv,D] -> [B*H, Hd, Lkv] -----------------
__global__ __launch_bounds__(256) void k_vtrans(const u16* __restrict__ V,
                                                u16* __restrict__ Vt) {
  int bh = blockIdx.y;
  int b = bh >> 4, h = bh & 15;
  int kv0 = blockIdx.x * 64;
  __shared__ __align__(16) u16 t[64][136];
  int tid = threadIdx.x;
  int r = tid >> 4, c = (tid & 15) * 8;
#pragma unroll
  for (int i = 0; i < 4; ++i) {
    int row = i * 16 + r;
    *(int4*)&t[row][c] = *(const int4*)&V[((size_t)b * LKV + kv0 + row) * DD + h * HDm + c];
  }
  __syncthreads();
  int hd_ = tid >> 3, kvc = (tid & 7) * 8;
#pragma unroll
  for (int i = 0; i < 4; ++i) {
    int hd = i * 32 + hd_;
    u16 tmp[8] __attribute__((aligned(16)));
#pragma unroll
    for (int j = 0; j < 8; ++j) tmp[j] = t[kvc + j][hd];
    *(int4*)&Vt[((size_t)bh * HDm + hd) * LKV + kv0 + kvc] = *(const int4*)tmp;
  }
}

// ---------------- fused attention ------------------------------------------
// 512 threads / 8 waves, q-tile 128, kv-tile 64. LDS: Ks dbuf 32K + Vs dbuf
// 32K + Ps 16K = 80K -> 2 blocks/CU. Raw barriers + counted vmcnt so Wout
// stores are NEVER drained inside the loop (16 newest ops stay in flight).
// Fixed softmax shift (|s|<=11.4 guaranteed by LN): pass A is sum-only.
__global__ __launch_bounds__(512, 4) void k_attn(const u16* __restrict__ Qp,
                                                 const u16* __restrict__ Kp,
                                                 const u16* __restrict__ Vt,
                                                 float* __restrict__ Wout,
                                                 u16* __restrict__ AO) {
  const int g = blockIdx.x;                 // 512 blocks, 8 XCDs, 64 each
  const int work = (g & 7) * 64 + (g >> 3);
  const int bh = work >> 4;
  const int b = bh >> 4, h = bh & 15;
  const int q0 = (work & 15) * 128;
  const int tid = threadIdx.x, w = tid >> 6, l = tid & 63;
  const int lr = l & 15, lk = (l >> 4) * 8, lrg = (l >> 4) * 4;
  const int rsw = (l & 7) << 3;             // read swizzle, u16 units
  __shared__ __align__(16) u16 Ks[2][64 * 128];
  __shared__ __align__(16) u16 Vs[2][128 * 64];
  __shared__ __align__(16) u16 Ps[8][16 * 64];

  // hoist Q fragments (A-frag: row = lr, k = lk + kc*32)
  bf8 qf[4];
  {
    const u16* qb = &Qp[((size_t)b * LQ + q0 + w * 16 + lr) * DD + h * HDm];
#pragma unroll
    for (int kc = 0; kc < 4; ++kc) qf[kc] = *(const bf8*)(qb + kc * 32 + lk);
  }
  const u16* Kb = Kp + (size_t)b * LKV * DD + h * HDm;   // row stride DD
  const u16* Vb = Vt + (size_t)bh * HDm * LKV;           // row (hd) stride LKV

  // staging (512 threads): K tile 64x128 -> 2 calls, V tile 128x64 -> 2 calls
  auto stageK = [&](int buf, int kv0) {
#pragma unroll
    for (int i = 0; i < 2; ++i) {
      int rbase = i * 32 + w * 4;           // wave-uniform
      int row = rbase + (l >> 4);
      int cb = ((l & 15) * 16) ^ ((row & 7) << 4);
      gl16((const char*)(Kb + (size_t)(kv0 + row) * DD) + cb, &Ks[buf][rbase * 128]);
    }
  };
  auto stageV = [&](int buf, int kv0) {
#pragma unroll
    for (int i = 0; i < 2; ++i) {
      int rbase = i * 64 + w * 8;
      int row = rbase + (l >> 3);
      int cb = ((l & 7) * 16) ^ ((row & 7) << 4);
      gl16((const char*)(Vb + (size_t)row * LKV + kv0) + cb, &Vs[buf][rbase * 64]);
    }
  };

  // ================= pass A: row sums of exp2(s*log2e - SHIFT2) ============
  float lsum[4] = {0.f, 0.f, 0.f, 0.f};
  stageK(0, 0);
  asm volatile("s_waitcnt vmcnt(0)" ::: "memory");
  barrier_hard();
  for (int t = 0; t < 64; ++t) {
    const int cur = t & 1;
    if (t < 63) stageK(cur ^ 1, (t + 1) * 64);   // prefetch next tile
    f32x4 s[4];
    __builtin_amdgcn_s_setprio(1);
#pragma unroll
    for (int ni = 0; ni < 4; ++ni) {
      s[ni] = f32x4{0.f, 0.f, 0.f, 0.f};
#pragma unroll
      for (int kc = 0; kc < 4; ++kc) {
        bf8 kf = *(const bf8*)&Ks[cur][(ni * 16 + lr) * 128 + ((kc * 32 + lk) ^ rsw)];
        s[ni] = mfma16(qf[kc], kf, s[ni]);
      }
    }
    __builtin_amdgcn_s_setprio(0);
#pragma unroll
    for (int ni = 0; ni < 4; ++ni)
#pragma unroll
      for (int r = 0; r < 4; ++r)
        lsum[r] += exp2f(fmaf(s[ni][r], LOG2E, -SHIFT2));
    asm volatile("s_waitcnt vmcnt(0)" ::: "memory");  // next tile staged
    barrier_hard();                                    // readers done, all staged
  }
  // reduce across the 16 lr lanes (per q-row)
  float inv[4];
#pragma unroll
  for (int r = 0; r < 4; ++r) {
    float v = lsum[r];
#pragma unroll
    for (int m = 1; m < 16; m <<= 1) v += __shfl_xor(v, m);
    inv[r] = 1.f / v;
  }

  // ================= pass B: weights + PV ===================================
  f32x4 oacc[8] = {};
  stageK(0, 0); stageV(0, 0);
  asm volatile("s_waitcnt vmcnt(0)" ::: "memory");
  barrier_hard();
  float* wbase = Wout + ((size_t)bh * LQ + q0 + w * 16 + lrg) * LKV;
  for (int t = 0; t < 64; ++t) {
    const int cur = t & 1;
    const int kv0 = t * 64;
    if (t < 63) {                            // prefetch next K,V (4 loads)
      stageK(cur ^ 1, kv0 + 64);
      stageV(cur ^ 1, kv0 + 64);
    }
    f32x4 s[4];
    __builtin_amdgcn_s_setprio(1);
#pragma unroll
    for (int ni = 0; ni < 4; ++ni) {
      s[ni] = f32x4{0.f, 0.f, 0.f, 0.f};
#pragma unroll
      for (int kc = 0; kc < 4; ++kc) {
        bf8 kf = *(const bf8*)&Ks[cur][(ni * 16 + lr) * 128 + ((kc * 32 + lk) ^ rsw)];
        s[ni] = mfma16(qf[kc], kf, s[ni]);
      }
    }
    __builtin_amdgcn_s_setprio(0);
    // normalized weights: fp32 nontemporal stores (16, stay in flight) + Ps
#pragma unroll
    for (int ni = 0; ni < 4; ++ni) {
#pragma unroll
      for (int r = 0; r < 4; ++r) {
        float p = exp2f(fmaf(s[ni][r], LOG2E, -SHIFT2)) * inv[r];
        __builtin_nontemporal_store(p, &wbase[(size_t)r * LKV + kv0 + ni * 16 + lr]);
        int row = lrg + r;
        Ps[w][row * 64 + ((ni * 16 + lr) ^ ((row & 7) << 3))] = f2bf(p);
      }
    }
    // Ps is per-wave: LDS wait only, no block barrier (rule #18 fence after)
    asm volatile("s_waitcnt lgkmcnt(0)" ::: "memory");
    __builtin_amdgcn_sched_barrier(0);
    __builtin_amdgcn_s_setprio(1);
#pragma unroll
    for (int kk = 0; kk < 2; ++kk) {
      bf8 pf = *(const bf8*)&Ps[w][lr * 64 + ((kk * 32 + lk) ^ rsw)];
#pragma unroll
      for (int c = 0; c < 8; ++c) {
        bf8 vf = *(const bf8*)&Vs[cur][(c * 16 + lr) * 64 + ((kk * 32 + lk) ^ rsw)];
        oacc[c] = mfma16(pf, vf, oacc[c]);
      }
    }
    __builtin_amdgcn_s_setprio(0);
    // drain the 4 prefetch loads (older) but leave the 16 stores in flight
    asm volatile("s_waitcnt vmcnt(16)" ::: "memory");
    barrier_hard();
  }
  // epilogue: AO [B, Lq, D] bf16 (re-read by O-proj -> normal stores)
#pragma unroll
  for (int c = 0; c < 8; ++c)
#pragma unroll
    for (int r = 0; r < 4; ++r)
      AO[((size_t)b * LQ + q0 + w * 16 + lrg + r) * DD + h * HDm + c * 16 + lr] =
          f2bf(oacc[c][r]);
}

// ---------------------------------------------------------------------------
extern "C" void kernel_launch(void* const* d_in, const int* in_sizes, int n_in,
                              void* d_out, int out_size, void* d_ws, size_t ws_size,
                              hipStream_t stream) {
  const float* hs   = (const float*)d_in[0];
  const float* cas  = (const float*)d_in[1];
  const float* q_w  = (const float*)d_in[2];
  const float* q_b  = (const float*)d_in[3];
  const float* k_w  = (const float*)d_in[4];
  const float* k_b  = (const float*)d_in[5];
  const float* v_w  = (const float*)d_in[6];
  const float* v_b  = (const float*)d_in[7];
  const float* o_w  = (const float*)d_in[8];
  const float* o_b  = (const float*)d_in[9];
  const float* qn_g = (const float*)d_in[10];
  const float* qn_b = (const float*)d_in[11];
  const float* kn_g = (const float*)d_in[12];
  const float* kn_b = (const float*)d_in[13];

  float* out_attn = (float*)d_out;
  float* out_w    = out_attn + (size_t)BB * LQ * DD;

  constexpr size_t SZ_Q  = (size_t)BB * LQ * DD * 2;
  constexpr size_t SZ_KV = (size_t)BB * LKV * DD * 2;
  constexpr size_t SZ_W  = (size_t)DD * DD * 2;
  char* p = (char*)d_ws;
  u16* hsb  = (u16*)p;              p += SZ_Q;
  u16* casb = (u16*)p;              p += SZ_KV;
  u16* qwb  = (u16*)p;              p += SZ_W;
  u16* kwb  = (u16*)p;              p += SZ_W;
  u16* vwb  = (u16*)p;              p += SZ_W;
  u16* owb  = (u16*)p;              p += SZ_W;
  u16* Qp   = (u16*)p;              p += SZ_Q;
  u16* Kp   = (u16*)p;              p += SZ_KV;
  u16* Vp   = (u16*)p;              p += SZ_KV;
  u16* Vtp  = (u16*)p;              p += SZ_KV;
  u16* AO   = (u16*)p;              p += SZ_Q;

  auto cvt = [&](const float* src, u16* dst, size_t n) {
    int n4 = (int)(n / 4);
    k_cvt<<<dim3((n4 + 255) / 256), dim3(256), 0, stream>>>(
        (const float4*)src, (ushort4*)dst, n4);
  };
  cvt(hs,  hsb,  (size_t)BB * LQ * DD);
  cvt(cas, casb, (size_t)BB * LKV * DD);
  cvt(q_w, qwb, (size_t)DD * DD);
  cvt(k_w, kwb, (size_t)DD * DD);
  cvt(v_w, vwb, (size_t)DD * DD);
  cvt(o_w, owb, (size_t)DD * DD);

  // projections; LN fused for Q (with ATTN_SCALE) and K
  k_gemm_nt<3><<<dim3(BB * LQ / 128, DD / 128), dim3(256), 0, stream>>>(
      hsb, qwb, q_b, qn_g, qn_b, Qp, BB * LQ, DD, DD);
  k_gemm_nt<2><<<dim3(BB * LKV / 128, DD / 128), dim3(256), 0, stream>>>(
      casb, kwb, k_b, kn_g, kn_b, Kp, BB * LKV, DD, DD);
  k_gemm_nt<0><<<dim3(BB * LKV / 128, DD / 128), dim3(256), 0, stream>>>(
      casb, vwb, v_b, nullptr, nullptr, Vp, BB * LKV, DD, DD);

  k_vtrans<<<dim3(LKV / 64, BB * NH), dim3(256), 0, stream>>>(Vp, Vtp);

  k_attn<<<dim3(LQ / 128 * BB * NH), dim3(512), 0, stream>>>(Qp, Kp, Vtp, out_w, AO);

  k_gemm_nt<1><<<dim3(BB * LQ / 128, DD / 128), dim3(256), 0, stream>>>(
      AO, owb, o_b, nullptr, nullptr, out_attn, BB * LQ, DD, DD);
}